// Round 1
// baseline (185.488 us; speedup 1.0000x reference)
//
#include <hip/hip_runtime.h>
#include <hip/hip_bf16.h>
#include <math.h>

#define BB   8
#define NN   512
#define DD   768
#define DEPD 64

// ---------------- kernel 1: s_nbr[b,j] = f·w_nbr, s_asp[b,j] = f·w_asp ----
__global__ __launch_bounds__(256) void k_proj(const float* __restrict__ feat,
                                              const float* __restrict__ watt,
                                              float* __restrict__ snbr,
                                              float* __restrict__ sasp)
{
    int flat = blockIdx.x * 4 + (threadIdx.x >> 6);   // b*N + j
    int lane = threadIdx.x & 63;
    const float* frow = feat + (size_t)flat * DD + lane * 4;
    const float* wn   = watt + lane * 4;              // w_nbr = w[:768]
    const float* wa   = watt + DD + DEPD + lane * 4;  // w_asp = w[832:1600]
    float accn = 0.f, acca = 0.f;
#pragma unroll
    for (int k = 0; k < 3; ++k) {
        float4 f = *(const float4*)(frow + k * 256);
        float4 n = *(const float4*)(wn + k * 256);
        float4 a = *(const float4*)(wa + k * 256);
        accn += f.x*n.x + f.y*n.y + f.z*n.z + f.w*n.w;
        acca += f.x*a.x + f.y*a.y + f.z*a.z + f.w*a.w;
    }
#pragma unroll
    for (int off = 1; off < 64; off <<= 1) {
        accn += __shfl_xor(accn, off);
        acca += __shfl_xor(acca, off);
    }
    if (lane == 0) { snbr[flat] = accn; sasp[flat] = acca; }
}

// ---------------- kernel 2: s_dep + mask + masked softmax -> weights ------
__global__ __launch_bounds__(256) void k_soft(const float* __restrict__ adj,
                                              const float* __restrict__ snbr,
                                              const float* __restrict__ sasp,
                                              const int* __restrict__ aspect,
                                              const float* __restrict__ watt,
                                              float* __restrict__ wts,
                                              int* __restrict__ upd)
{
    int bi  = blockIdx.x;          // b*N + i
    int b   = bi >> 9;
    int tid = threadIdx.x;
    int g = tid >> 4, l = tid & 15;

    __shared__ float sdep[NN];
    __shared__ int   smsk[NN];
    __shared__ float sred[4];

    float4 wd = *(const float4*)(watt + DD + l * 4);   // w_dep = w[768:832]

    const float* arow = adj + (size_t)bi * NN * DEPD;
#pragma unroll 4
    for (int it = 0; it < NN / 16; ++it) {
        int j = it * 16 + g;
        float4 a = *(const float4*)(arow + (size_t)j * DEPD + l * 4);
        float p  = a.x*wd.x + a.y*wd.y + a.z*wd.z + a.w*wd.w;
        int   nz = (a.x != 0.f) | (a.y != 0.f) | (a.z != 0.f) | (a.w != 0.f);
#pragma unroll
        for (int off = 1; off < 16; off <<= 1) {
            p  += __shfl_xor(p, off);
            nz |= __shfl_xor(nz, off);
        }
        if (l == 0) { sdep[j] = p; smsk[j] = nz; }
    }
    __syncthreads();

    float sa = sasp[bi];
    int j0 = tid, j1 = tid + 256;
    float sc0 = sdep[j0] + snbr[(b << 9) + j0] + sa;
    float sc1 = sdep[j1] + snbr[(b << 9) + j1] + sa;
    int m0 = smsk[j0], m1 = smsk[j1];

    // block-wide max over masked scores
    float v = fmaxf(m0 ? sc0 : -INFINITY, m1 ? sc1 : -INFINITY);
#pragma unroll
    for (int off = 1; off < 64; off <<= 1) v = fmaxf(v, __shfl_xor(v, off));
    if ((tid & 63) == 0) sred[tid >> 6] = v;
    __syncthreads();
    float mx = fmaxf(fmaxf(sred[0], sred[1]), fmaxf(sred[2], sred[3]));
    __syncthreads();

    float e0 = m0 ? __expf(sc0 - mx) : 0.f;
    float e1 = m1 ? __expf(sc1 - mx) : 0.f;
    v = e0 + e1;
#pragma unroll
    for (int off = 1; off < 64; off <<= 1) v += __shfl_xor(v, off);
    if ((tid & 63) == 0) sred[tid >> 6] = v;
    __syncthreads();
    float sm = sred[0] + sred[1] + sred[2] + sred[3];

    float inv = sm > 0.f ? 1.f / sm : 0.f;
    size_t wb = (size_t)bi * NN;
    wts[wb + j0] = e0 * inv;
    wts[wb + j1] = e1 * inv;
    if (tid == 0) upd[bi] = (aspect[bi] != 0) && (mx > -1e37f);
}

// ---------------- kernel 3: out = upd ? weights@features : features ------
__global__ __launch_bounds__(256) void k_agg(const float* __restrict__ feat,
                                             const float* __restrict__ wts,
                                             const int* __restrict__ upd,
                                             float* __restrict__ out)
{
    int b   = blockIdx.z;
    int i0  = blockIdx.y * 16;
    int d   = blockIdx.x * 256 + threadIdx.x;
    int tid = threadIdx.x;

    // weights tile, j-major with stride 20 floats (80 B: 16B-aligned rows,
    // staging writes spread over 8 banks; main-loop reads are uniform-addr
    // broadcasts so padding doesn't matter there)
    __shared__ __align__(16) float wl[NN * 20];

    const float* wbase = wts + ((size_t)(b * NN + i0)) * NN;
#pragma unroll
    for (int k = 0; k < 32; ++k) {
        int e  = k * 256 + tid;
        int ii = e >> 9;        // uniform within an iteration
        int j  = e & 511;       // consecutive across lanes -> coalesced
        wl[j * 20 + ii] = wbase[(size_t)ii * NN + j];
    }
    __syncthreads();

    float acc[16];
#pragma unroll
    for (int ii = 0; ii < 16; ++ii) acc[ii] = 0.f;

    const float* fcol = feat + (size_t)(b * NN) * DD + d;
#pragma unroll 4
    for (int j = 0; j < NN; ++j) {
        float f = fcol[(size_t)j * DD];
        const float4* wp = (const float4*)(wl + j * 20);
        float4 w0 = wp[0], w1 = wp[1], w2 = wp[2], w3 = wp[3];
        acc[0]  = fmaf(w0.x, f, acc[0]);
        acc[1]  = fmaf(w0.y, f, acc[1]);
        acc[2]  = fmaf(w0.z, f, acc[2]);
        acc[3]  = fmaf(w0.w, f, acc[3]);
        acc[4]  = fmaf(w1.x, f, acc[4]);
        acc[5]  = fmaf(w1.y, f, acc[5]);
        acc[6]  = fmaf(w1.z, f, acc[6]);
        acc[7]  = fmaf(w1.w, f, acc[7]);
        acc[8]  = fmaf(w2.x, f, acc[8]);
        acc[9]  = fmaf(w2.y, f, acc[9]);
        acc[10] = fmaf(w2.z, f, acc[10]);
        acc[11] = fmaf(w2.w, f, acc[11]);
        acc[12] = fmaf(w3.x, f, acc[12]);
        acc[13] = fmaf(w3.y, f, acc[13]);
        acc[14] = fmaf(w3.z, f, acc[14]);
        acc[15] = fmaf(w3.w, f, acc[15]);
    }

#pragma unroll
    for (int ii = 0; ii < 16; ++ii) {
        int row = b * NN + i0 + ii;
        float o = upd[row] ? acc[ii] : feat[(size_t)row * DD + d];
        out[(size_t)row * DD + d] = o;
    }
}

extern "C" void kernel_launch(void* const* d_in, const int* in_sizes, int n_in,
                              void* d_out, int out_size, void* d_ws, size_t ws_size,
                              hipStream_t stream)
{
    (void)in_sizes; (void)n_in; (void)out_size; (void)ws_size;
    const float* feat = (const float*)d_in[0];
    const int*   asp  = (const int*)d_in[1];
    const float* adj  = (const float*)d_in[2];
    const float* watt = (const float*)d_in[3];
    float* out = (float*)d_out;

    // workspace layout: snbr[4096] | sasp[4096] | upd[4096] | wts[8M floats]
    float* snbr = (float*)d_ws;
    float* sasp = snbr + BB * NN;
    int*   upd  = (int*)(sasp + BB * NN);
    float* wts  = (float*)(upd + BB * NN);

    k_proj<<<BB * NN / 4, 256, 0, stream>>>(feat, watt, snbr, sasp);
    k_soft<<<BB * NN, 256, 0, stream>>>(adj, snbr, sasp, asp, watt, wts, upd);
    dim3 g3(DD / 256, NN / 16, BB);
    k_agg<<<g3, 256, 0, stream>>>(feat, wts, upd, out);
}